// Round 2
// baseline (231.115 us; speedup 1.0000x reference)
//
#include <hip/hip_runtime.h>
#include <hip/hip_bf16.h>
#include <cstdint>

using u16 = unsigned short;
using u32 = unsigned int;

typedef __bf16 bf16x8 __attribute__((ext_vector_type(8)));
typedef float  f32x4  __attribute__((ext_vector_type(4)));

__device__ __forceinline__ u16 f2b(float f) {
    u32 u = __builtin_bit_cast(u32, f);
    u += 0x7fffu + ((u >> 16) & 1u);
    return (u16)(u >> 16);
}

// async global->LDS, 16B per lane; lds dst is wave-uniform base + lane*16
__device__ __forceinline__ void gload_lds16(const u16* g, u16* l) {
    __builtin_amdgcn_global_load_lds(
        (const __attribute__((address_space(1))) void*)g,
        (__attribute__((address_space(3))) void*)l,
        16, 0, 0);
}

// ---------------------------------------------------------------------------
// pack: fp32 -> bf16 casts (x, Wq|Wk concat, Wv, Wo) + bias concat bq|bk
// ---------------------------------------------------------------------------
__launch_bounds__(256)
__global__ void pack_kernel(const float* __restrict__ x,
                            const float* __restrict__ Wq,
                            const float* __restrict__ Wk,
                            const float* __restrict__ Wv,
                            const float* __restrict__ Wo,
                            const float* __restrict__ bq,
                            const float* __restrict__ bk,
                            u16* __restrict__ xb,
                            u16* __restrict__ Wqkb,
                            u16* __restrict__ Wvb,
                            u16* __restrict__ Wob,
                            float* __restrict__ bqk)
{
    int c = blockIdx.x * 256 + threadIdx.x;   // 0 .. 1081343
    long e = (long)c * 8;
    const float* src; u16* dst; long off;
    if (e < 6291456L)      { src = x;  dst = xb;            off = e; }
    else if (e < 6881280L) { src = Wq; dst = Wqkb;          off = e - 6291456L; }
    else if (e < 7471104L) { src = Wk; dst = Wqkb + 589824; off = e - 6881280L; }
    else if (e < 8060928L) { src = Wv; dst = Wvb;           off = e - 7471104L; }
    else                   { src = Wo; dst = Wob;           off = e - 8060928L; }
    float4 v0 = *(const float4*)(src + off);
    float4 v1 = *(const float4*)(src + off + 4);
    union { u16 u[8]; uint4 q; } o;
    o.u[0] = f2b(v0.x); o.u[1] = f2b(v0.y); o.u[2] = f2b(v0.z); o.u[3] = f2b(v0.w);
    o.u[4] = f2b(v1.x); o.u[5] = f2b(v1.y); o.u[6] = f2b(v1.z); o.u[7] = f2b(v1.w);
    *(uint4*)(dst + off) = o.q;
    if (c < 768)       bqk[c] = bq[c];
    else if (c < 1536) bqk[c] = bk[c - 768];
}

// ---------------------------------------------------------------------------
// gemm_bt: C[m,n] = sum_k A[m,k] * B[n,k]  (both A,B bf16 K-contiguous)
// 128x128 tile, 256 threads (4 waves, each 64x64 = 4x4 mfma_16x16x32_bf16)
// Staging via global_load_lds width=16 (m97 pattern).
// MODE 0: bf16 out, + bias[col]
// MODE 1: bf16 out, + bias[row]
// MODE 2: f32 out, *scale, diag(-1e9) within group tile (M=N=512)
// MODE 3: bf16 out, no bias
// MODE 4: f32 out, out = xres + beta*(acc + bias[col])
// M,N multiples of 128; K multiple of 32. blockIdx = (ntile, mtile, group)
// ---------------------------------------------------------------------------
template<int MODE>
__launch_bounds__(256)
__global__ void gemm_bt(const u16* __restrict__ A, int lda, long sAz,
                        const u16* __restrict__ B, int ldb, long sBz,
                        void* __restrict__ Cv, int ldc, long sCz,
                        int K,
                        const float* __restrict__ bias,
                        const float* __restrict__ xres,
                        const float* __restrict__ betaPtr,
                        float scale)
{
    __shared__ u16 As[128 * 32];
    __shared__ u16 Bs[128 * 32];

    const int tid  = threadIdx.x;
    const int g    = blockIdx.z;
    const u16* Ab = A + (long)g * sAz + (long)blockIdx.y * 128 * lda;
    const u16* Bb = B + (long)g * sBz + (long)blockIdx.x * 128 * ldb;

    const int wave = tid >> 6, lane = tid & 63;
    const int wm = (wave >> 1) * 64, wn = (wave & 1) * 64;
    const int ln15 = lane & 15, lq = lane >> 4;

    f32x4 acc[4][4];
#pragma unroll
    for (int i = 0; i < 4; i++)
#pragma unroll
        for (int j = 0; j < 4; j++)
            acc[i][j] = (f32x4){0.f, 0.f, 0.f, 0.f};

    // async staging: per wave, 2 chunks of 1024B per operand per K-step.
    // chunk c covers tile elements [c*512, c*512+512): row = c*16+(lane>>2),
    // col = (lane&3)*8. LDS dst = base + lane*16 (hardware), layout linear.
    const int c0 = wave * 2, c1 = wave * 2 + 1;
    const int sr0 = c0 * 16 + (lane >> 2), sc = (lane & 3) * 8;
    const int sr1 = c1 * 16 + (lane >> 2);
    const u16* Ag0 = Ab + (long)sr0 * lda + sc;
    const u16* Ag1 = Ab + (long)sr1 * lda + sc;
    const u16* Bg0 = Bb + (long)sr0 * ldb + sc;
    const u16* Bg1 = Bb + (long)sr1 * ldb + sc;
    u16* Al0 = As + c0 * 512;  u16* Al1 = As + c1 * 512;
    u16* Bl0 = Bs + c0 * 512;  u16* Bl1 = Bs + c1 * 512;

    for (int k0 = 0; k0 < K; k0 += 32) {
        __syncthreads();              // prior iteration's LDS reads complete
        gload_lds16(Ag0 + k0, Al0);
        gload_lds16(Ag1 + k0, Al1);
        gload_lds16(Bg0 + k0, Bl0);
        gload_lds16(Bg1 + k0, Bl1);
        __syncthreads();              // drains vmcnt: tiles resident

        bf16x8 af[4], bfr[4];
#pragma unroll
        for (int i = 0; i < 4; i++)
            af[i] = *(const bf16x8*)&As[(wm + i * 16 + ln15) * 32 + lq * 8];
#pragma unroll
        for (int j = 0; j < 4; j++)
            bfr[j] = *(const bf16x8*)&Bs[(wn + j * 16 + ln15) * 32 + lq * 8];
#pragma unroll
        for (int i = 0; i < 4; i++)
#pragma unroll
            for (int j = 0; j < 4; j++)
                acc[i][j] = __builtin_amdgcn_mfma_f32_16x16x32_bf16(af[i], bfr[j], acc[i][j], 0, 0, 0);
    }

    const int baseRow = blockIdx.y * 128 + wm;
    const int baseCol = blockIdx.x * 128 + wn;

    if constexpr (MODE == 0 || MODE == 1 || MODE == 3) {
        u16* C = (u16*)Cv + (long)g * sCz;
#pragma unroll
        for (int i = 0; i < 4; i++)
#pragma unroll
            for (int j = 0; j < 4; j++)
#pragma unroll
                for (int r = 0; r < 4; r++) {
                    int row = baseRow + i * 16 + lq * 4 + r;
                    int col = baseCol + j * 16 + ln15;
                    float v = acc[i][j][r];
                    if constexpr (MODE == 0) v += bias[col];
                    if constexpr (MODE == 1) v += bias[row];
                    C[(long)row * ldc + col] = f2b(v);
                }
    } else if constexpr (MODE == 2) {
        float* C = (float*)Cv + (long)g * sCz;
#pragma unroll
        for (int i = 0; i < 4; i++)
#pragma unroll
            for (int j = 0; j < 4; j++)
#pragma unroll
                for (int r = 0; r < 4; r++) {
                    int row = baseRow + i * 16 + lq * 4 + r;
                    int col = baseCol + j * 16 + ln15;
                    float v = acc[i][j][r] * scale;
                    if (row == col) v = -1.0e9f;
                    C[(long)row * ldc + col] = v;
                }
    } else { // MODE 4
        float* C = (float*)Cv;
        float bet = betaPtr[0];
#pragma unroll
        for (int i = 0; i < 4; i++)
#pragma unroll
            for (int j = 0; j < 4; j++)
#pragma unroll
                for (int r = 0; r < 4; r++) {
                    int row = baseRow + i * 16 + lq * 4 + r;
                    int col = baseCol + j * 16 + ln15;
                    float v = xres[(long)row * ldc + col] + bet * (acc[i][j][r] + bias[col]);
                    C[(long)row * ldc + col] = v;
                }
    }
}

// ---------------------------------------------------------------------------
// row softmax over 512 entries, one wave per row; S fp32 -> P bf16
// ---------------------------------------------------------------------------
__launch_bounds__(256)
__global__ void softmax_rows(const float* __restrict__ S, u16* __restrict__ P)
{
    int row  = blockIdx.x * 4 + (threadIdx.x >> 6);
    int lane = threadIdx.x & 63;
    const float* s = S + (long)row * 512 + lane * 8;
    float4 v0 = *(const float4*)s;
    float4 v1 = *(const float4*)(s + 4);
    float vv[8] = {v0.x, v0.y, v0.z, v0.w, v1.x, v1.y, v1.z, v1.w};
    float m = vv[0];
#pragma unroll
    for (int i = 1; i < 8; i++) m = fmaxf(m, vv[i]);
#pragma unroll
    for (int off = 32; off; off >>= 1) m = fmaxf(m, __shfl_xor(m, off));
    float e[8], sum = 0.f;
#pragma unroll
    for (int i = 0; i < 8; i++) { e[i] = __expf(vv[i] - m); sum += e[i]; }
#pragma unroll
    for (int off = 32; off; off >>= 1) sum += __shfl_xor(sum, off);
    float inv = 1.0f / sum;
    union { u16 u[8]; uint4 q; } o;
#pragma unroll
    for (int i = 0; i < 8; i++) o.u[i] = f2b(e[i] * inv);
    *(uint4*)(P + (long)row * 512 + lane * 8) = o.q;
}

// ---------------------------------------------------------------------------
// launch
// ---------------------------------------------------------------------------
extern "C" void kernel_launch(void* const* d_in, const int* in_sizes, int n_in,
                              void* d_out, int out_size, void* d_ws, size_t ws_size,
                              hipStream_t stream)
{
    const float* x    = (const float*)d_in[0];
    // d_in[1] = batch (contiguous groups of 512; structure hardcoded)
    const float* Wq   = (const float*)d_in[2];
    const float* bq   = (const float*)d_in[3];
    const float* Wk   = (const float*)d_in[4];
    const float* bk   = (const float*)d_in[5];
    const float* Wv   = (const float*)d_in[6];
    const float* bv   = (const float*)d_in[7];
    const float* Wo   = (const float*)d_in[8];
    const float* bo   = (const float*)d_in[9];
    const float* beta = (const float*)d_in[10];
    float* out = (float*)d_out;

    char* ws = (char*)d_ws;
    // workspace layout (bytes), lifetime-based overlays; total 67,639,296 B
    u16*   qk   = (u16*)(ws + 0);            // [8192,1536] bf16, live GEMM1->GEMM3
    u16*   dyn  = (u16*)(ws + 0);            // [8192,768]  bf16, live GEMM4->GEMM5 (aliases qk)
    u16*   vT   = (u16*)(ws + 25165824);     // [768,8192]  bf16
    u16*   Wqkb = (u16*)(ws + 37748736);     // [1536,768]  bf16
    u16*   Wvb  = (u16*)(ws + 40108032);     // [768,768]   bf16
    u16*   Wob  = (u16*)(ws + 41287680);     // [768,768]   bf16
    float* bqk  = (float*)(ws + 42467328);   // [1536] f32
    u16*   xb   = (u16*)(ws + 42473472);     // [8192,768] bf16, live pack->GEMM2
    float* S    = (float*)(ws + 42473472);   // [8192,512] f32, live GEMM3->softmax (aliases xb)
    u16*   P    = (u16*)(ws + 59250688);     // [8192,512] bf16

    const float scale = 0.03608439182435161f;  // 1/sqrt(768)

    pack_kernel<<<4224, 256, 0, stream>>>(x, Wq, Wk, Wv, Wo, bq, bk,
                                          xb, Wqkb, Wvb, Wob, bqk);

    // q|k = xb @ Wqk^T + bqk : [8192,1536]
    gemm_bt<0><<<dim3(12, 64, 1), 256, 0, stream>>>(
        xb, 768, 0, Wqkb, 768, 0, (void*)qk, 1536, 0, 768, bqk, nullptr, nullptr, 0.f);

    // vT = Wv @ xb^T + bv[row] : [768,8192]
    gemm_bt<1><<<dim3(64, 6, 1), 256, 0, stream>>>(
        Wvb, 768, 0, xb, 768, 0, (void*)vT, 8192, 0, 768, bv, nullptr, nullptr, 0.f);

    // per-group scores: S[g*512+m, n] = scale * q_g[m,:] . k_g[n,:], diag=-1e9
    gemm_bt<2><<<dim3(4, 4, 16), 256, 0, stream>>>(
        qk, 1536, 512L * 1536, qk + 768, 1536, 512L * 1536,
        (void*)S, 512, 512L * 512, 768, nullptr, nullptr, nullptr, scale);

    softmax_rows<<<2048, 256, 0, stream>>>(S, P);

    // dyn_g = P_g @ v_g : A=P [512,512] bf16, B=vT rows (K-contig), [512,768]
    gemm_bt<3><<<dim3(6, 4, 16), 256, 0, stream>>>(
        P, 512, 512L * 512, vT, 8192, 512L,
        (void*)dyn, 768, 512L * 768, 512, nullptr, nullptr, nullptr, 0.f);

    // out = x + beta * (dyn @ Wo^T + bo)
    gemm_bt<4><<<dim3(6, 64, 1), 256, 0, stream>>>(
        dyn, 768, 0, Wob, 768, 0, (void*)out, 768, 0, 768, bo, x, beta, 0.f);
}

// Round 3
// 220.623 us; speedup vs baseline: 1.0476x; 1.0476x over previous
//
#include <hip/hip_runtime.h>
#include <hip/hip_bf16.h>
#include <cstdint>

using u16 = unsigned short;
using u32 = unsigned int;

typedef __bf16 bf16x8 __attribute__((ext_vector_type(8)));
typedef float  f32x4  __attribute__((ext_vector_type(4)));

__device__ __forceinline__ u16 f2b(float f) {
    u32 u = __builtin_bit_cast(u32, f);
    u += 0x7fffu + ((u >> 16) & 1u);
    return (u16)(u >> 16);
}

// async global->LDS, 16B per lane; lds dst is wave-uniform base + lane*16
__device__ __forceinline__ void gload_lds16(const u16* g, u16* l) {
    __builtin_amdgcn_global_load_lds(
        (const __attribute__((address_space(1))) void*)g,
        (__attribute__((address_space(3))) void*)l,
        16, 0, 0);
}

// ---------------------------------------------------------------------------
// pack: fp32 -> bf16 casts (x, Wq|Wk|Wv concat, Wo) + bias concat bq|bk|bv
// segments (elements): x 6291456 | Wq/Wk/Wv -> Wqkv 1769472 | Wo 589824
// ---------------------------------------------------------------------------
__launch_bounds__(256)
__global__ void pack_kernel(const float* __restrict__ x,
                            const float* __restrict__ Wq,
                            const float* __restrict__ Wk,
                            const float* __restrict__ Wv,
                            const float* __restrict__ Wo,
                            const float* __restrict__ bq,
                            const float* __restrict__ bk,
                            const float* __restrict__ bv,
                            u16* __restrict__ xb,
                            u16* __restrict__ Wqkvb,
                            u16* __restrict__ Wob,
                            float* __restrict__ bqkv)
{
    int c = blockIdx.x * 256 + threadIdx.x;   // 0 .. 1081343
    long e = (long)c * 8;
    const float* src; u16* dst; long off;
    if (e < 6291456L)      { src = x;  dst = xb;              off = e; }
    else if (e < 6881280L) { src = Wq; dst = Wqkvb;           off = e - 6291456L; }
    else if (e < 7471104L) { src = Wk; dst = Wqkvb + 589824;  off = e - 6881280L; }
    else if (e < 8060928L) { src = Wv; dst = Wqkvb + 1179648; off = e - 7471104L; }
    else                   { src = Wo; dst = Wob;             off = e - 8060928L; }
    float4 v0 = *(const float4*)(src + off);
    float4 v1 = *(const float4*)(src + off + 4);
    union { u16 u[8]; uint4 q; } o;
    o.u[0] = f2b(v0.x); o.u[1] = f2b(v0.y); o.u[2] = f2b(v0.z); o.u[3] = f2b(v0.w);
    o.u[4] = f2b(v1.x); o.u[5] = f2b(v1.y); o.u[6] = f2b(v1.z); o.u[7] = f2b(v1.w);
    *(uint4*)(dst + off) = o.q;
    if (c < 768)        bqkv[c] = bq[c];
    else if (c < 1536)  bqkv[c] = bk[c - 768];
    else if (c < 2304)  bqkv[c] = bv[c - 1536];
}

// ---------------------------------------------------------------------------
// gemm_bt: C[m,n] = sum_k A[m,k] * B[n,k]  (A,B bf16 K-contiguous)
// 128x128 tile, 256 threads (4 waves, 4x4 mfma_16x16x32_bf16 each),
// double-buffered LDS, one barrier per K-step, global_load_lds staging.
// MODE 0: QKV: cols<1536 -> bf16 +bias to C (ldc); cols>=1536 -> transposed
//         ushort4 store (+bias) to vTout [768,8192]
// MODE 2: f32 out, *scale, local diag(-1e9)  (scores, M=N=512 per group)
// MODE 3: bf16 out, no bias                  (PV)
// MODE 4: f32 out, out = xres + beta*(acc + bias[col])
// M,N multiples of 128; K multiple of 32. blockIdx = (ntile, mtile, group)
// ---------------------------------------------------------------------------
template<int MODE>
__launch_bounds__(256)
__global__ void gemm_bt(const u16* __restrict__ A, int lda, long sAz,
                        const u16* __restrict__ B, int ldb, long sBz,
                        void* __restrict__ Cv, int ldc, long sCz,
                        int K,
                        const float* __restrict__ bias,
                        const float* __restrict__ xres,
                        const float* __restrict__ betaPtr,
                        float scale,
                        u16* __restrict__ vTout)
{
    __shared__ u16 As[2][128 * 32];
    __shared__ u16 Bs[2][128 * 32];

    const int tid  = threadIdx.x;
    const int g    = blockIdx.z;
    const u16* Ab = A + (long)g * sAz + (long)blockIdx.y * 128 * lda;
    const u16* Bb = B + (long)g * sBz + (long)blockIdx.x * 128 * ldb;

    const int wave = tid >> 6, lane = tid & 63;
    const int wm = (wave >> 1) * 64, wn = (wave & 1) * 64;
    const int ln15 = lane & 15, lq = lane >> 4;

    f32x4 acc[4][4];
#pragma unroll
    for (int i = 0; i < 4; i++)
#pragma unroll
        for (int j = 0; j < 4; j++)
            acc[i][j] = (f32x4){0.f, 0.f, 0.f, 0.f};

    // per wave: 2 chunks of 1024B per operand per K-step; chunk c covers
    // rows [c*16, c*16+16), lane i -> row c*16+i/4, col (i%4)*8; LDS dst
    // = base + lane*16 (hardware scatter), layout linear.
    const int c0 = wave * 2, c1 = wave * 2 + 1;
    const int sr0 = c0 * 16 + (lane >> 2), sc = (lane & 3) * 8;
    const int sr1 = c1 * 16 + (lane >> 2);
    const u16* Ag0 = Ab + (long)sr0 * lda + sc;
    const u16* Ag1 = Ab + (long)sr1 * lda + sc;
    const u16* Bg0 = Bb + (long)sr0 * ldb + sc;
    const u16* Bg1 = Bb + (long)sr1 * ldb + sc;

    const int nk = K >> 5;

    // prefetch K-step 0 into buffer 0
    gload_lds16(Ag0, &As[0][c0 * 512]);
    gload_lds16(Ag1, &As[0][c1 * 512]);
    gload_lds16(Bg0, &Bs[0][c0 * 512]);
    gload_lds16(Bg1, &Bs[0][c1 * 512]);

    for (int kt = 0; kt < nk; kt++) {
        const int cur = kt & 1;
        __syncthreads();          // drains loads into buf[cur] + prior ds_reads
        if (kt + 1 < nk) {        // prefetch next K-step into the other buffer
            const int k0 = (kt + 1) * 32, nxt = cur ^ 1;
            gload_lds16(Ag0 + k0, &As[nxt][c0 * 512]);
            gload_lds16(Ag1 + k0, &As[nxt][c1 * 512]);
            gload_lds16(Bg0 + k0, &Bs[nxt][c0 * 512]);
            gload_lds16(Bg1 + k0, &Bs[nxt][c1 * 512]);
        }

        bf16x8 af[4], bfr[4];
#pragma unroll
        for (int i = 0; i < 4; i++)
            af[i] = *(const bf16x8*)&As[cur][(wm + i * 16 + ln15) * 32 + lq * 8];
#pragma unroll
        for (int j = 0; j < 4; j++)
            bfr[j] = *(const bf16x8*)&Bs[cur][(wn + j * 16 + ln15) * 32 + lq * 8];
#pragma unroll
        for (int i = 0; i < 4; i++)
#pragma unroll
            for (int j = 0; j < 4; j++)
                acc[i][j] = __builtin_amdgcn_mfma_f32_16x16x32_bf16(af[i], bfr[j], acc[i][j], 0, 0, 0);
    }

    const int baseRow = blockIdx.y * 128 + wm;
    const int baseCol = blockIdx.x * 128 + wn;

    if constexpr (MODE == 0) {
        if (baseCol < 1536) {     // q|k columns -> qk buffer
            u16* C = (u16*)Cv;
#pragma unroll
            for (int i = 0; i < 4; i++)
#pragma unroll
                for (int j = 0; j < 4; j++)
#pragma unroll
                    for (int r = 0; r < 4; r++) {
                        int row = baseRow + i * 16 + lq * 4 + r;
                        int col = baseCol + j * 16 + ln15;
                        C[(long)row * ldc + col] = f2b(acc[i][j][r] + bias[col]);
                    }
        } else {                  // v columns -> transposed into vT [768,8192]
#pragma unroll
            for (int i = 0; i < 4; i++)
#pragma unroll
                for (int j = 0; j < 4; j++) {
                    int col = baseCol + j * 16 + ln15;
                    float bb = bias[col];
                    ushort4 o;
                    o.x = f2b(acc[i][j][0] + bb);
                    o.y = f2b(acc[i][j][1] + bb);
                    o.z = f2b(acc[i][j][2] + bb);
                    o.w = f2b(acc[i][j][3] + bb);
                    *(ushort4*)(vTout + (long)(col - 1536) * 8192
                                + baseRow + i * 16 + lq * 4) = o;
                }
        }
    } else if constexpr (MODE == 2) {
        float* C = (float*)Cv + (long)g * sCz;
#pragma unroll
        for (int i = 0; i < 4; i++)
#pragma unroll
            for (int j = 0; j < 4; j++)
#pragma unroll
                for (int r = 0; r < 4; r++) {
                    int row = baseRow + i * 16 + lq * 4 + r;
                    int col = baseCol + j * 16 + ln15;
                    float v = acc[i][j][r] * scale;
                    if (row == col) v = -1.0e9f;
                    C[(long)row * ldc + col] = v;
                }
    } else if constexpr (MODE == 3) {
        u16* C = (u16*)Cv + (long)g * sCz;
#pragma unroll
        for (int i = 0; i < 4; i++)
#pragma unroll
            for (int j = 0; j < 4; j++)
#pragma unroll
                for (int r = 0; r < 4; r++) {
                    int row = baseRow + i * 16 + lq * 4 + r;
                    int col = baseCol + j * 16 + ln15;
                    C[(long)row * ldc + col] = f2b(acc[i][j][r]);
                }
    } else { // MODE 4
        float* C = (float*)Cv;
        float bet = betaPtr[0];
#pragma unroll
        for (int i = 0; i < 4; i++)
#pragma unroll
            for (int j = 0; j < 4; j++)
#pragma unroll
                for (int r = 0; r < 4; r++) {
                    int row = baseRow + i * 16 + lq * 4 + r;
                    int col = baseCol + j * 16 + ln15;
                    float v = xres[(long)row * ldc + col] + bet * (acc[i][j][r] + bias[col]);
                    C[(long)row * ldc + col] = v;
                }
    }
}

// ---------------------------------------------------------------------------
// row softmax over 512 entries, one wave per row; S fp32 -> P bf16
// ---------------------------------------------------------------------------
__launch_bounds__(256)
__global__ void softmax_rows(const float* __restrict__ S, u16* __restrict__ P)
{
    int row  = blockIdx.x * 4 + (threadIdx.x >> 6);
    int lane = threadIdx.x & 63;
    const float* s = S + (long)row * 512 + lane * 8;
    float4 v0 = *(const float4*)s;
    float4 v1 = *(const float4*)(s + 4);
    float vv[8] = {v0.x, v0.y, v0.z, v0.w, v1.x, v1.y, v1.z, v1.w};
    float m = vv[0];
#pragma unroll
    for (int i = 1; i < 8; i++) m = fmaxf(m, vv[i]);
#pragma unroll
    for (int off = 32; off; off >>= 1) m = fmaxf(m, __shfl_xor(m, off));
    float e[8], sum = 0.f;
#pragma unroll
    for (int i = 0; i < 8; i++) { e[i] = __expf(vv[i] - m); sum += e[i]; }
#pragma unroll
    for (int off = 32; off; off >>= 1) sum += __shfl_xor(sum, off);
    float inv = 1.0f / sum;
    union { u16 u[8]; uint4 q; } o;
#pragma unroll
    for (int i = 0; i < 8; i++) o.u[i] = f2b(e[i] * inv);
    *(uint4*)(P + (long)row * 512 + lane * 8) = o.q;
}

// ---------------------------------------------------------------------------
// launch
// ---------------------------------------------------------------------------
extern "C" void kernel_launch(void* const* d_in, const int* in_sizes, int n_in,
                              void* d_out, int out_size, void* d_ws, size_t ws_size,
                              hipStream_t stream)
{
    const float* x    = (const float*)d_in[0];
    // d_in[1] = batch (contiguous groups of 512; structure hardcoded)
    const float* Wq   = (const float*)d_in[2];
    const float* bq   = (const float*)d_in[3];
    const float* Wk   = (const float*)d_in[4];
    const float* bk   = (const float*)d_in[5];
    const float* Wv   = (const float*)d_in[6];
    const float* bv   = (const float*)d_in[7];
    const float* Wo   = (const float*)d_in[8];
    const float* bo   = (const float*)d_in[9];
    const float* beta = (const float*)d_in[10];
    float* out = (float*)d_out;

    char* ws = (char*)d_ws;
    // workspace layout (bytes), lifetime overlays; high-water ~67.64 MB
    u16*   qk    = (u16*)(ws + 0);            // [8192,1536] bf16, QKV->scores
    u16*   dyn   = (u16*)(ws + 0);            // [8192,768]  bf16, PV->out (aliases qk)
    u16*   vT    = (u16*)(ws + 25165824);     // [768,8192]  bf16
    u16*   Wqkvb = (u16*)(ws + 37748736);     // [2304,768]  bf16
    u16*   Wob   = (u16*)(ws + 41287680);     // [768,768]   bf16
    float* bqkv  = (float*)(ws + 42467328);   // [2304] f32
    u16*   xb    = (u16*)(ws + 42476544);     // [8192,768] bf16, pack->QKV
    float* S     = (float*)(ws + 42476544);   // [8192,512] f32, scores->softmax (aliases xb)
    u16*   P     = (u16*)(ws + 59253760);     // [8192,512] bf16

    const float scale = 0.03608439182435161f;  // 1/sqrt(768)

    pack_kernel<<<4224, 256, 0, stream>>>(x, Wq, Wk, Wv, Wo, bq, bk, bv,
                                          xb, Wqkvb, Wob, bqkv);

    // qkv = xb @ Wqkv^T + bqkv : q|k -> qk [8192,1536]; v -> vT [768,8192] transposed
    gemm_bt<0><<<dim3(18, 64, 1), 256, 0, stream>>>(
        xb, 768, 0, Wqkvb, 768, 0, (void*)qk, 1536, 0, 768, bqkv, nullptr, nullptr, 0.f, vT);

    // per-group scores: S = scale * q_g k_g^T, local diag = -1e9
    gemm_bt<2><<<dim3(4, 4, 16), 256, 0, stream>>>(
        qk, 1536, 512L * 1536, qk + 768, 1536, 512L * 1536,
        (void*)S, 512, 512L * 512, 768, nullptr, nullptr, nullptr, scale, nullptr);

    softmax_rows<<<2048, 256, 0, stream>>>(S, P);

    // dyn_g = P_g @ v_g : A=P [512,512], B=vT (K-contig along n), [512,768]
    gemm_bt<3><<<dim3(6, 4, 16), 256, 0, stream>>>(
        P, 512, 512L * 512, vT, 8192, 512L,
        (void*)dyn, 768, 512L * 768, 512, nullptr, nullptr, nullptr, 0.f, nullptr);

    // out = x + beta * (dyn @ Wo^T + bo)
    gemm_bt<4><<<dim3(6, 64, 1), 256, 0, stream>>>(
        dyn, 768, 0, Wob, 768, 0, (void*)out, 768, 0, 768, bo, x, beta, 0.f, nullptr);
}